// Round 3
// baseline (666.824 us; speedup 1.0000x reference)
//
#include <hip/hip_runtime.h>
#include <math.h>

// LearnableFlatPool: out[b,c,i,j] = max_{ki,kj} f[b,c,2i+ki,2j+kj] + h[c,ki,kj]
// h collapses per channel: center=0, edge=-(1/t)^16, corner=-(2/t)^16.
//
// Row-wise decomposition: for input row r and a 4-col group (float4 v, tap e):
//   outer(r) = max(v.x+hC, v.y+hE, v.z+hC)   (r = top/bottom of a window)
//   mid(r)   = max(v.x+hE, v.y,    v.z+hE)   (r = middle of a window)
// out(i) = max(outer(2i), mid(2i+1), outer(2i+2)) — even rows are shared by
// two vertically-adjacent outputs, so a rolling `prevOuter` register gives
// perfect vertical reuse: 2.03 input rows loaded per output row.
//
// Mapping: thread = (rowTile rt in 0..2, plane bc, colTile jt in 0..55).
// 111 = 3*37 output rows/tile. All 64 lanes of every wave load a full 16 B
// dwordx4; a wave's row load is one contiguous 896 B run (+128 B next plane).

namespace {
constexpr int Bn = 16, Cn = 128, Hn = 224, Wn = 224;
constexpr int Ho = 111, Wo = 111;
constexpr int TILE = 37;              // output rows per thread (111 = 3*37)
constexpr int CT = 56;                // float4 col-tiles per row (224/4)
constexpr int PLANES = Bn * Cn;       // 2048
}

__global__ __launch_bounds__(256) void lfp_kernel(const float* __restrict__ f,
                                                  const float* __restrict__ t,
                                                  float* __restrict__ out) {
    const int tid  = blockIdx.x * 256 + threadIdx.x;
    const int flat = tid % (PLANES * CT);
    const int rt   = tid / (PLANES * CT);     // 0..2 (vertical tile)
    const int bc   = flat / CT;
    const int jt   = flat % CT;
    const int c    = bc & (Cn - 1);

    // Per-channel h constants (pow by squaring).
    const float tc = t[c];
    const float xe = 1.0f / tc, xc = 2.0f / tc;
    float e2 = xe * xe, e4 = e2 * e2, e8 = e4 * e4;
    float c2 = xc * xc, c4 = c2 * c2, c8 = c4 * c4;
    const float hE = -(e8 * e8);   // edge taps
    const float hC = -(c8 * c8);   // corner taps

    const int col  = 4 * jt;
    const int ecol = (col + 4 < Wn) ? col + 4 : Wn - 1; // lane jt=55: tap unused
    const bool oddValid = (2 * jt + 1) < Wo;

    const float* plane  = f + (size_t)bc * Hn * Wn;
    float*       oplane = out + (size_t)bc * Ho * Wo;

    const int i0 = rt * TILE;

    // Preload outer row 2*i0.
    {
    }
    const float* r0 = plane + (size_t)(2 * i0) * Wn;
    float4 v0 = *(const float4*)(r0 + col);
    float  t0 = r0[ecol];
    float prevOuterA = fmaxf(fmaxf(v0.x + hC, v0.y + hE), v0.z + hC);
    float prevOuterB = fmaxf(fmaxf(v0.z + hC, v0.w + hE), t0 + hC);

    for (int ii = 0; ii < TILE; ++ii) {
        const int i = i0 + ii;
        const float* rm = plane + (size_t)(2 * i + 1) * Wn; // middle row
        const float* rb = plane + (size_t)(2 * i + 2) * Wn; // bottom (next outer)
        float4 vm = *(const float4*)(rm + col);
        float  em = rm[ecol];
        float4 vb = *(const float4*)(rb + col);
        float  eb = rb[ecol];

        float midA = fmaxf(fmaxf(vm.x + hE, vm.y), vm.z + hE);
        float midB = fmaxf(fmaxf(vm.z + hE, vm.w), em + hE);
        float outA = fmaxf(fmaxf(vb.x + hC, vb.y + hE), vb.z + hC);
        float outB = fmaxf(fmaxf(vb.z + hC, vb.w + hE), eb + hC);

        float oA = fmaxf(fmaxf(prevOuterA, midA), outA);
        float oB = fmaxf(fmaxf(prevOuterB, midB), outB);
        prevOuterA = outA;
        prevOuterB = outB;

        float* orow = oplane + (size_t)i * Wo + 2 * jt;
        __builtin_nontemporal_store(oA, orow);
        if (oddValid) __builtin_nontemporal_store(oB, orow + 1);
    }
}

extern "C" void kernel_launch(void* const* d_in, const int* in_sizes, int n_in,
                              void* d_out, int out_size, void* d_ws, size_t ws_size,
                              hipStream_t stream) {
    const float* f = (const float*)d_in[0];
    const float* t = (const float*)d_in[1];
    float* out = (float*)d_out;

    const int total  = 3 * PLANES * CT;          // 344064 threads, exact
    const int blocks = total / 256;              // 1344
    lfp_kernel<<<dim3(blocks), dim3(256), 0, stream>>>(f, t, out);
}